// Round 2
// baseline (2651.203 us; speedup 1.0000x reference)
//
#include <hip/hip_runtime.h>
#include <math.h>

// Problem constants (shapes from reference); N/NNZ/E derived from in_sizes at launch.
#define HEADS 4
#define HD 32      // per-head out dim
#define QD 64      // type query dim
#define DIN 128    // in_dim == hidden_dim
#define NTYPES 4
#define ETYPES 3

static inline int cdiv(int a, int b){ return (a + b - 1) / b; }

// ---------------- preprocessing: counting sort by edge and by node ----------------

__global__ __launch_bounds__(256) void hist_k(const int* __restrict__ node_idx,
                                              const int* __restrict__ edge_idx,
                                              int* __restrict__ cnt_e, int* __restrict__ cnt_n, int NNZ)
{
  int i = blockIdx.x*256 + threadIdx.x;
  if (i < NNZ){
    atomicAdd(&cnt_e[edge_idx[i]], 1);
    atomicAdd(&cnt_n[node_idx[i]], 1);
  }
}

__global__ __launch_bounds__(1024) void scan_pass1(const int* __restrict__ in, int* __restrict__ bsums, int n)
{
  __shared__ int sd[1024];
  int i = blockIdx.x*1024 + threadIdx.x;
  sd[threadIdx.x] = (i < n) ? in[i] : 0;
  __syncthreads();
  for (int s = 512; s > 0; s >>= 1){
    if (threadIdx.x < s) sd[threadIdx.x] += sd[threadIdx.x + s];
    __syncthreads();
  }
  if (threadIdx.x == 0) bsums[blockIdx.x] = sd[0];
}

__global__ __launch_bounds__(1024) void scan_pass2(int* __restrict__ bsums, int nb)
{
  __shared__ int sd[1024];
  int v = (threadIdx.x < nb) ? bsums[threadIdx.x] : 0;
  sd[threadIdx.x] = v;
  __syncthreads();
  for (int s = 1; s < 1024; s <<= 1){
    int t = (threadIdx.x >= s) ? sd[threadIdx.x - s] : 0;
    __syncthreads();
    sd[threadIdx.x] += t;
    __syncthreads();
  }
  if (threadIdx.x < nb) bsums[threadIdx.x] = sd[threadIdx.x] - v;  // exclusive
}

__global__ __launch_bounds__(1024) void scan_pass3(const int* __restrict__ in, const int* __restrict__ bsums,
                                                   int* __restrict__ out, int n)
{
  __shared__ int sd[1024];
  int i = blockIdx.x*1024 + threadIdx.x;
  int v = (i < n) ? in[i] : 0;
  sd[threadIdx.x] = v;
  __syncthreads();
  for (int s = 1; s < 1024; s <<= 1){
    int t = (threadIdx.x >= s) ? sd[threadIdx.x - s] : 0;
    __syncthreads();
    sd[threadIdx.x] += t;
    __syncthreads();
  }
  if (i < n) out[i] = bsums[blockIdx.x] + sd[threadIdx.x] - v;  // exclusive offsets
}

// Scatter: build both sorted index structures + the edge-sorted -> node-sorted map.
__global__ __launch_bounds__(256) void scatter_k(const int* __restrict__ node_idx, const int* __restrict__ edge_idx,
                                                 const int* __restrict__ edge_off, const int* __restrict__ node_off,
                                                 int* __restrict__ cur_e, int* __restrict__ cur_n,
                                                 int* __restrict__ pos_e, int* __restrict__ nidx_srtE,
                                                 int* __restrict__ map_e2n, int* __restrict__ eidx_srtN, int NNZ)
{
  int i = blockIdx.x*256 + threadIdx.x;
  if (i >= NNZ) return;
  int n = node_idx[i], e = edge_idx[i];
  int pe = edge_off[e] + atomicAdd(&cur_e[e], 1);
  int pn = node_off[n] + atomicAdd(&cur_n[n], 1);
  pos_e[i]      = pe;
  nidx_srtE[pe] = n;
  eidx_srtN[pn] = e;
  map_e2n[pe]   = pn;
}

// ---------------- K1: per-node per-head features: alpha gate, Q, V ----------------

__global__ __launch_bounds__(256) void k1_feats(
    const float* __restrict__ h, int hstride,
    const int* __restrict__ node_types,
    const float* __restrict__ tq,   // [H][NTYPES][QD]
    const float* __restrict__ w1,   // [H][DIN+QD][32]
    const float* __restrict__ b1,   // [H][32]
    const float* __restrict__ w2,   // [H][32]
    const float* __restrict__ b2,   // [H]
    const float* __restrict__ wq,   // [H][DIN][HD]
    const float* __restrict__ wv,   // [H][DIN][HD]
    float* __restrict__ Qs, float* __restrict__ Vs, float* __restrict__ alpha_out, int N)
{
  int n = blockIdx.x*256 + threadIdx.x;
  int hh = blockIdx.y;
  if (n >= N) return;

  const float4* hr = reinterpret_cast<const float4*>(h + (size_t)n * hstride);
  float4 hreg[32];
  #pragma unroll
  for (int k = 0; k < 32; k++) hreg[k] = hr[k];

  int ty = node_types[n];
  const float4* sp = reinterpret_cast<const float4*>(tq + ((size_t)hh*NTYPES + ty)*QD);
  float4 sreg[16];
  #pragma unroll
  for (int k = 0; k < 16; k++) sreg[k] = sp[k];

  const float* w1h = w1 + (size_t)hh*(DIN+QD)*32;
  float acc2 = b2[hh];
  for (int j = 0; j < 32; j++){
    float acc = b1[hh*32 + j];
    #pragma unroll
    for (int k = 0; k < 32; k++){
      float4 hv = hreg[k];
      const float* wr = w1h + (4*k)*32 + j;
      acc += hv.x*wr[0] + hv.y*wr[32] + hv.z*wr[64] + hv.w*wr[96];
    }
    #pragma unroll
    for (int k = 0; k < 16; k++){
      float4 sv = sreg[k];
      const float* wr = w1h + (DIN + 4*k)*32 + j;
      acc += sv.x*wr[0] + sv.y*wr[32] + sv.z*wr[64] + sv.w*wr[96];
    }
    float z = tanhf(acc);
    acc2 += z * w2[hh*32 + j];
  }
  float al = 1.0f / (1.0f + __expf(-acc2));
  alpha_out[(size_t)hh*N + n] = al;

  const float* wqh = wq + (size_t)hh*DIN*HD;
  const float* wvh = wv + (size_t)hh*DIN*HD;
  float4* Qrow = reinterpret_cast<float4*>(Qs + ((size_t)hh*N + n)*HD);
  float4* Vrow = reinterpret_cast<float4*>(Vs + ((size_t)hh*N + n)*HD);
  for (int d4 = 0; d4 < 8; d4++){
    float4 q = make_float4(0.f,0.f,0.f,0.f);
    float4 vv = make_float4(0.f,0.f,0.f,0.f);
    #pragma unroll
    for (int k = 0; k < 32; k++){
      float4 hv = hreg[k];
      const float4* wq0 = reinterpret_cast<const float4*>(wqh + (size_t)(4*k)*32 + d4*4);
      const float4* wv0 = reinterpret_cast<const float4*>(wvh + (size_t)(4*k)*32 + d4*4);
      float4 a0 = wq0[0], a1 = wq0[8], a2 = wq0[16], a3 = wq0[24];  // rows stride 32 floats = 8 float4
      q.x += hv.x*a0.x + hv.y*a1.x + hv.z*a2.x + hv.w*a3.x;
      q.y += hv.x*a0.y + hv.y*a1.y + hv.z*a2.y + hv.w*a3.y;
      q.z += hv.x*a0.z + hv.y*a1.z + hv.z*a2.z + hv.w*a3.z;
      q.w += hv.x*a0.w + hv.y*a1.w + hv.z*a2.w + hv.w*a3.w;
      float4 c0 = wv0[0], c1 = wv0[8], c2 = wv0[16], c3 = wv0[24];
      vv.x += hv.x*c0.x + hv.y*c1.x + hv.z*c2.x + hv.w*c3.x;
      vv.y += hv.x*c0.y + hv.y*c1.y + hv.z*c2.y + hv.w*c3.y;
      vv.z += hv.x*c0.z + hv.y*c1.z + hv.z*c2.z + hv.w*c3.z;
      vv.w += hv.x*c0.w + hv.y*c1.w + hv.z*c2.w + hv.w*c3.w;
    }
    Qrow[d4] = q; Vrow[d4] = vv;
  }
}

// ---------------- K2a: per-nnz raw attention logits (all heads), written edge-sorted ----------------

__global__ __launch_bounds__(256) void k2a(
    const float* __restrict__ Qs, const float* __restrict__ alpha,
    const int* __restrict__ node_idx, const int* __restrict__ edge_idx, const int* __restrict__ edge_type,
    const float* __restrict__ ec,   // [H][ETYPES][HD]
    const int* __restrict__ pos_e,
    float* __restrict__ a_srtE, int NNZ, int N)
{
  int i = blockIdx.x*256 + threadIdx.x;
  if (i >= NNZ) return;
  int n = node_idx[i], e = edge_idx[i];
  int et = edge_type[e];
  int pe = pos_e[i];
  for (int hh = 0; hh < HEADS; hh++){
    const float4* qrow = reinterpret_cast<const float4*>(Qs + ((size_t)hh*N + n)*HD);
    const float4* crow = reinterpret_cast<const float4*>(ec + (size_t)(hh*ETYPES + et)*HD);
    float s = 0.f;
    #pragma unroll
    for (int k = 0; k < 8; k++){
      float4 q = qrow[k], c = crow[k];
      s += q.x*c.x + q.y*c.y + q.z*c.z + q.w*c.w;
    }
    s = (s >= 0.f) ? s : 0.2f*s;                 // leaky_relu(0.2)
    s *= alpha[(size_t)hh*N + n];
    a_srtE[(size_t)hh*NNZ + pe] = s;
  }
}

// ---------------- K2b: per-(edge,head) wave: segment softmax + edge_feat ----------------

__global__ __launch_bounds__(256) void k2b(
    const float* __restrict__ a_srtE, const int* __restrict__ nidx_srtE,
    const int* __restrict__ edge_off, const int* __restrict__ cnt_e,
    const float* __restrict__ Vs, const int* __restrict__ map_e2n,
    float* __restrict__ edge_feat, float* __restrict__ attn_srtN, int NNZ, int N, int E)
{
  int e = blockIdx.x;
  int hh = threadIdx.x >> 6;      // wave id = head
  int lane = threadIdx.x & 63;
  int off = edge_off[e], cnt = cnt_e[e];
  if (cnt == 0) return;

  const float* a = a_srtE + (size_t)hh*NNZ + off;

  // phase 1: segment max (register-resident)
  float m = -INFINITY;
  for (int j = lane; j < cnt; j += 64) m = fmaxf(m, a[j]);
  #pragma unroll
  for (int s = 32; s > 0; s >>= 1) m = fmaxf(m, __shfl_xor(m, s));

  // phase 2: exp-sum and unnormalized edge_feat; half-wave per entry, lane&31 = dim
  int p = lane >> 5, d = lane & 31;
  float ef = 0.f, ssum = 0.f;
  for (int jj = 0; jj < cnt; jj += 2){
    int j = jj + p;
    if (j < cnt){
      float ex = __expf(a[j] - m);
      int n = nidx_srtE[off + j];
      ef += ex * Vs[((size_t)hh*N + n)*HD + d];
      ssum += ex;
    }
  }
  ef += __shfl_xor(ef, 32);
  float stot = ssum + __shfl_xor(ssum, 32);
  float inv = 1.0f / stot;
  if (lane < 32) edge_feat[((size_t)hh*E + e)*HD + d] = ef * inv;

  // phase 3: store normalized attn directly into node-sorted order
  for (int j = lane; j < cnt; j += 64){
    float ex = __expf(a[j] - m);
    attn_srtN[(size_t)hh*NNZ + map_e2n[off + j]] = ex * inv;
  }
}

// ---------------- K2c: per-node block: aggregate + concat heads + residual + LayerNorm ----------------

__global__ __launch_bounds__(128) void k2c(
    const float* __restrict__ attn_srtN, const int* __restrict__ eidx_srtN,
    const int* __restrict__ node_off, const int* __restrict__ cnt_n,
    const float* __restrict__ edge_feat,
    const float* __restrict__ h_in, int hstride,
    const float* __restrict__ ln_g, const float* __restrict__ ln_b,
    float* __restrict__ out, int out_stride, int out_col, int NNZ, int N, int E)
{
  int n = blockIdx.x;
  int t = threadIdx.x;          // 0..127 : head = t>>5, dim = t&31
  int hh = t >> 5, d = t & 31;
  int off = node_off[n], cnt = cnt_n[n];
  const float* attn = attn_srtN + (size_t)hh*NNZ;
  float nf = 0.f;
  for (int j = 0; j < cnt; j++){
    float av = attn[off + j];
    int e = eidx_srtN[off + j];
    nf += av * edge_feat[((size_t)hh*E + e)*HD + d];
  }
  float hn = nf + h_in[(size_t)n*hstride + t];   // residual (IN==HID)

  __shared__ float sred[2];
  float s = hn;
  #pragma unroll
  for (int sh = 32; sh > 0; sh >>= 1) s += __shfl_xor(s, sh);
  if ((t & 63) == 0) sred[t >> 6] = s;
  __syncthreads();
  float mu = (sred[0] + sred[1]) * (1.0f/128.0f);
  __syncthreads();
  float dv = hn - mu;
  float s2 = dv*dv;
  #pragma unroll
  for (int sh = 32; sh > 0; sh >>= 1) s2 += __shfl_xor(s2, sh);
  if ((t & 63) == 0) sred[t >> 6] = s2;
  __syncthreads();
  float var = (sred[0] + sred[1]) * (1.0f/128.0f);
  float r = rsqrtf(var + 1e-5f);
  out[(size_t)n*out_stride + out_col + t] = dv * r * ln_g[t] + ln_b[t];
}

// ---------------- x copy into output columns 0..127 ----------------

__global__ __launch_bounds__(256) void xcopy_k(const float* __restrict__ x, float* __restrict__ out, int N)
{
  int i = blockIdx.x*256 + threadIdx.x;   // over N*32 float4s
  if (i >= N*32) return;
  int n = i >> 5, k = i & 31;
  reinterpret_cast<float4*>(out)[(size_t)n*96 + k] = reinterpret_cast<const float4*>(x)[i];
}

// ---------------- launcher ----------------

extern "C" void kernel_launch(void* const* d_in, const int* in_sizes, int n_in,
                              void* d_out, int out_size, void* d_ws, size_t ws_size,
                              hipStream_t stream)
{
  const float* x          = (const float*)d_in[0];
  const int*   node_types = (const int*)  d_in[1];
  const int*   node_idx   = (const int*)  d_in[2];
  const int*   edge_idx   = (const int*)  d_in[3];
  const int*   edge_type  = (const int*)  d_in[4];
  const float* type_query = (const float*)d_in[5];
  const float* fc1_w      = (const float*)d_in[6];
  const float* fc1_b      = (const float*)d_in[7];
  const float* fc2_w      = (const float*)d_in[8];
  const float* fc2_b      = (const float*)d_in[9];
  const float* Wq         = (const float*)d_in[10];
  const float* Wv         = (const float*)d_in[11];
  const float* edge_ctx   = (const float*)d_in[12];
  const float* ln_g       = (const float*)d_in[13];
  const float* ln_b       = (const float*)d_in[14];

  const int N   = in_sizes[1];
  const int NNZ = in_sizes[2];
  const int E   = in_sizes[4];
  const int L   = 2;

  char* ws = (char*)d_ws;
  size_t o = 0;
  auto alloc = [&](size_t bytes)->void*{
    void* p = ws + o;
    o = (o + bytes + 255) & ~(size_t)255;
    return p;
  };
  int* cnt_e     = (int*)alloc((size_t)E*4);
  int* cur_e     = (int*)alloc((size_t)E*4);
  int* edge_off  = (int*)alloc((size_t)(E+1)*4);
  int* cnt_n     = (int*)alloc((size_t)N*4);
  int* cur_n     = (int*)alloc((size_t)N*4);
  int* node_off  = (int*)alloc((size_t)(N+1)*4);
  int* pos_e     = (int*)alloc((size_t)NNZ*4);
  int* nidx_srtE = (int*)alloc((size_t)NNZ*4);
  int* map_e2n   = (int*)alloc((size_t)NNZ*4);
  int* eidx_srtN = (int*)alloc((size_t)NNZ*4);
  int* bsum      = (int*)alloc((size_t)1024*4);
  float* a_srtE    = (float*)alloc((size_t)HEADS*NNZ*4);
  float* attn_srtN = (float*)alloc((size_t)HEADS*NNZ*4);
  float* Qs        = (float*)alloc((size_t)HEADS*N*HD*4);
  float* Vs        = (float*)alloc((size_t)HEADS*N*HD*4);
  float* alphaA    = (float*)alloc((size_t)HEADS*N*4);
  float* edge_featA= (float*)alloc((size_t)HEADS*E*HD*4);
  if (o > ws_size) return;  // insufficient workspace: bail loudly (output stays wrong)

  hipMemsetAsync(cnt_e, 0, (size_t)E*4, stream);
  hipMemsetAsync(cur_e, 0, (size_t)E*4, stream);
  hipMemsetAsync(cnt_n, 0, (size_t)N*4, stream);
  hipMemsetAsync(cur_n, 0, (size_t)N*4, stream);

  hist_k<<<cdiv(NNZ,256),256,0,stream>>>(node_idx, edge_idx, cnt_e, cnt_n, NNZ);

  int nbE = cdiv(E,1024), nbN = cdiv(N,1024);
  scan_pass1<<<nbE,1024,0,stream>>>(cnt_e, bsum, E);
  scan_pass2<<<1,1024,0,stream>>>(bsum, nbE);
  scan_pass3<<<nbE,1024,0,stream>>>(cnt_e, bsum, edge_off, E);
  scan_pass1<<<nbN,1024,0,stream>>>(cnt_n, bsum, N);
  scan_pass2<<<1,1024,0,stream>>>(bsum, nbN);
  scan_pass3<<<nbN,1024,0,stream>>>(cnt_n, bsum, node_off, N);

  scatter_k<<<cdiv(NNZ,256),256,0,stream>>>(node_idx, edge_idx, edge_off, node_off,
                                            cur_e, cur_n, pos_e, nidx_srtE, map_e2n, eidx_srtN, NNZ);

  xcopy_k<<<cdiv(N*32,256),256,0,stream>>>(x, (float*)d_out, N);

  for (int l = 0; l < L; l++){
    const float* hin = (l == 0) ? x : ((const float*)d_out + 128);
    int hstride = (l == 0) ? DIN : (DIN + 2*DIN);   // 128 or 384

    k1_feats<<<dim3(cdiv(N,256),HEADS),256,0,stream>>>(
        hin, hstride, node_types,
        type_query + (size_t)l*HEADS*NTYPES*QD,
        fc1_w + (size_t)l*HEADS*(DIN+QD)*32,
        fc1_b + (size_t)l*HEADS*32,
        fc2_w + (size_t)l*HEADS*32,
        fc2_b + (size_t)l*HEADS,
        Wq + (size_t)l*HEADS*DIN*HD,
        Wv + (size_t)l*HEADS*DIN*HD,
        Qs, Vs, alphaA, N);

    k2a<<<cdiv(NNZ,256),256,0,stream>>>(Qs, alphaA, node_idx, edge_idx, edge_type,
                                        edge_ctx + (size_t)l*HEADS*ETYPES*HD, pos_e,
                                        a_srtE, NNZ, N);

    k2b<<<E,256,0,stream>>>(a_srtE, nidx_srtE, edge_off, cnt_e, Vs, map_e2n,
                            edge_featA, attn_srtN, NNZ, N, E);

    k2c<<<N,128,0,stream>>>(attn_srtN, eidx_srtN, node_off, cnt_n, edge_featA,
                            hin, hstride,
                            ln_g + (size_t)l*DIN, ln_b + (size_t)l*DIN,
                            (float*)d_out, 3*DIN, DIN + l*DIN, NNZ, N, E);
  }
}

// Round 3
// 1272.623 us; speedup vs baseline: 2.0833x; 2.0833x over previous
//
#include <hip/hip_runtime.h>
#include <math.h>

#define HEADS 4
#define HD 32      // per-head out dim
#define QD 64      // type query dim
#define DIN 128    // in_dim == hidden_dim
#define NTYPES 4
#define ETYPES 3

typedef __attribute__((ext_vector_type(8))) short bf16x8;
typedef __attribute__((ext_vector_type(4))) float f32x4;

static inline int cdiv(int a, int b){ return (a + b - 1) / b; }

__device__ inline unsigned short f2bf(float f){
  unsigned u = __float_as_uint(f);
  unsigned r = (u + 0x7FFF + ((u >> 16) & 1)) >> 16;   // RNE
  return (unsigned short)r;
}

// ---------------- preprocessing: counting sort by edge and by node ----------------

__global__ __launch_bounds__(256) void hist_k(const int* __restrict__ node_idx,
                                              const int* __restrict__ edge_idx,
                                              int* __restrict__ cnt_e, int* __restrict__ cnt_n, int NNZ)
{
  int i = blockIdx.x*256 + threadIdx.x;
  if (i < NNZ){
    atomicAdd(&cnt_e[edge_idx[i]], 1);
    atomicAdd(&cnt_n[node_idx[i]], 1);
  }
}

__global__ __launch_bounds__(1024) void scan_pass1(const int* __restrict__ in, int* __restrict__ bsums, int n)
{
  __shared__ int sd[1024];
  int i = blockIdx.x*1024 + threadIdx.x;
  sd[threadIdx.x] = (i < n) ? in[i] : 0;
  __syncthreads();
  for (int s = 512; s > 0; s >>= 1){
    if (threadIdx.x < s) sd[threadIdx.x] += sd[threadIdx.x + s];
    __syncthreads();
  }
  if (threadIdx.x == 0) bsums[blockIdx.x] = sd[0];
}

__global__ __launch_bounds__(1024) void scan_pass2(int* __restrict__ bsums, int nb)
{
  __shared__ int sd[1024];
  int v = (threadIdx.x < nb) ? bsums[threadIdx.x] : 0;
  sd[threadIdx.x] = v;
  __syncthreads();
  for (int s = 1; s < 1024; s <<= 1){
    int t = (threadIdx.x >= s) ? sd[threadIdx.x - s] : 0;
    __syncthreads();
    sd[threadIdx.x] += t;
    __syncthreads();
  }
  if (threadIdx.x < nb) bsums[threadIdx.x] = sd[threadIdx.x] - v;  // exclusive
}

__global__ __launch_bounds__(1024) void scan_pass3(const int* __restrict__ in, const int* __restrict__ bsums,
                                                   int* __restrict__ out, int n)
{
  __shared__ int sd[1024];
  int i = blockIdx.x*1024 + threadIdx.x;
  int v = (i < n) ? in[i] : 0;
  sd[threadIdx.x] = v;
  __syncthreads();
  for (int s = 1; s < 1024; s <<= 1){
    int t = (threadIdx.x >= s) ? sd[threadIdx.x - s] : 0;
    __syncthreads();
    sd[threadIdx.x] += t;
    __syncthreads();
  }
  if (i < n) out[i] = bsums[blockIdx.x] + sd[threadIdx.x] - v;  // exclusive offsets
}

__global__ __launch_bounds__(256) void scatter_k(const int* __restrict__ node_idx, const int* __restrict__ edge_idx,
                                                 const int* __restrict__ edge_off, const int* __restrict__ node_off,
                                                 int* __restrict__ cur_e, int* __restrict__ cur_n,
                                                 int* __restrict__ pos_e, int* __restrict__ nidx_srtE,
                                                 int* __restrict__ map_e2n, int* __restrict__ eidx_srtN, int NNZ)
{
  int i = blockIdx.x*256 + threadIdx.x;
  if (i >= NNZ) return;
  int n = node_idx[i], e = edge_idx[i];
  int pe = edge_off[e] + atomicAdd(&cur_e[e], 1);
  int pn = node_off[n] + atomicAdd(&cur_n[n], 1);
  pos_e[i]      = pe;
  nidx_srtE[pe] = n;
  eidx_srtN[pn] = e;
  map_e2n[pe]   = pn;
}

// ---------------- weight prep: Wt[384][128] bf16 (col-major fragments), sbias ----------------

// Wt col layout: c in [0,128): fc1 (hh=c>>5, j=c&31); [128,256): Wq; [256,384): Wv
__global__ __launch_bounds__(128) void wtprep_k(const float* __restrict__ w1, const float* __restrict__ wq,
                                                const float* __restrict__ wv, short* __restrict__ Wt, int L)
{
  int c = blockIdx.x % 384, l = blockIdx.x / 384;
  int k = threadIdx.x;
  int sec = c >> 7;
  int hh = (c >> 5) & 3, j = c & 31;
  float v;
  if (sec == 0)      v = w1[((((size_t)l*HEADS + hh)*(DIN+QD)) + k)*32 + j];
  else if (sec == 1) v = wq[((((size_t)l*HEADS + hh)*DIN) + k)*32 + j];
  else               v = wv[((((size_t)l*HEADS + hh)*DIN) + k)*32 + j];
  Wt[((size_t)l*384 + c)*128 + k] = (short)f2bf(v);
}

// sbias[l][hh][ty][j] = b1 + sig @ w1[128:192]
__global__ __launch_bounds__(32) void sbias_k(const float* __restrict__ tq, const float* __restrict__ w1,
                                              const float* __restrict__ b1, float* __restrict__ sbias)
{
  int b = blockIdx.x;
  int ty = b % NTYPES; int hh = (b / NTYPES) % HEADS; int l = b / (NTYPES*HEADS);
  int j = threadIdx.x;
  const float* tqp = tq + (((size_t)l*HEADS + hh)*NTYPES + ty)*QD;
  const float* w1p = w1 + ((size_t)l*HEADS + hh)*(DIN+QD)*32;
  float s = b1[((size_t)l*HEADS + hh)*32 + j];
  for (int k = 0; k < QD; k++) s += tqp[k] * w1p[(size_t)(DIN + k)*32 + j];
  sbias[(size_t)b*32 + j] = s;
}

// ---------------- K1 replacement: MFMA GEMM h[N,128] @ Wt^T -> {alpha, Q, V} ----------------
// grid (cdiv(N,128), 3): blockIdx.y: 0 = fc1 (fused alpha epilogue), 1 = Q, 2 = V
// 4 waves, each 64 rows x 64 cols of the 128x128 tile.

__global__ __launch_bounds__(256) void gemm_k(
    const float* __restrict__ h, int hstride,
    const short* __restrict__ Wt,          // [384][128] bf16 (this layer)
    const int* __restrict__ node_types,
    const float* __restrict__ sbias,       // [H][NTYPES][32]
    const float* __restrict__ w2,          // [H][32]
    const float* __restrict__ b2,          // [H]
    float* __restrict__ feat,              // [N][256]: cols 0-127 Q, 128-255 V
    float* __restrict__ alphaA,            // [H][N]
    int N)
{
  int lane = threadIdx.x & 63, wv = threadIdx.x >> 6;
  int wr = wv >> 1, wc = wv & 1;
  int l15 = lane & 15, l4 = lane >> 4;
  int rbase = blockIdx.x*128 + wr*64;
  int ct = blockIdx.y;

  f32x4 acc[4][4] = {};

  #pragma unroll
  for (int kk = 0; kk < 4; kk++){
    bf16x8 a[4], b[4];
    #pragma unroll
    for (int mf = 0; mf < 4; mf++){
      int row = rbase + mf*16 + l15;
      int rr = (row < N) ? row : (N-1);             // clamp: pad rows give garbage acc, never stored
      const float* pa = h + (size_t)rr*hstride + kk*32 + l4*8;
      float4 f0 = *(const float4*)pa;
      float4 f1 = *(const float4*)(pa + 4);
      a[mf][0] = (short)f2bf(f0.x); a[mf][1] = (short)f2bf(f0.y);
      a[mf][2] = (short)f2bf(f0.z); a[mf][3] = (short)f2bf(f0.w);
      a[mf][4] = (short)f2bf(f1.x); a[mf][5] = (short)f2bf(f1.y);
      a[mf][6] = (short)f2bf(f1.z); a[mf][7] = (short)f2bf(f1.w);
    }
    #pragma unroll
    for (int cf = 0; cf < 4; cf++){
      int col = ct*128 + wc*64 + cf*16 + l15;
      b[cf] = *(const bf16x8*)(Wt + (size_t)col*128 + kk*32 + l4*8);
    }
    #pragma unroll
    for (int mf = 0; mf < 4; mf++)
      #pragma unroll
      for (int cf = 0; cf < 4; cf++)
        acc[mf][cf] = __builtin_amdgcn_mfma_f32_16x16x32_bf16(a[mf], b[cf], acc[mf][cf], 0, 0, 0);
  }

  if (ct){
    // store Q (ct=1) / V (ct=2) into feat[N][256]
    int cb = (ct - 1)*128 + wc*64;
    #pragma unroll
    for (int mf = 0; mf < 4; mf++){
      #pragma unroll
      for (int r = 0; r < 4; r++){
        int row = rbase + mf*16 + l4*4 + r;
        if (row < N){
          float* o = feat + (size_t)row*256 + cb;
          #pragma unroll
          for (int cf = 0; cf < 4; cf++) o[cf*16 + l15] = acc[mf][cf][r];
        }
      }
    }
  } else {
    // fused fc1 -> tanh -> fc2 -> sigmoid epilogue; D frag: row=(l>>4)*4+r, col=l&15
    #pragma unroll
    for (int mf = 0; mf < 4; mf++){
      int rw[4], ty[4];
      #pragma unroll
      for (int r = 0; r < 4; r++){
        rw[r] = rbase + mf*16 + l4*4 + r;
        ty[r] = (rw[r] < N) ? node_types[rw[r]] : 0;
      }
      #pragma unroll
      for (int p = 0; p < 2; p++){
        int hh = wc*2 + p;
        float w2a = w2[hh*32 + l15];
        float w2b = w2[hh*32 + 16 + l15];
        float b2v = b2[hh];
        #pragma unroll
        for (int r = 0; r < 4; r++){
          const float* sb = sbias + ((size_t)hh*NTYPES + ty[r])*32;
          float z0 = acc[mf][2*p  ][r] + sb[l15];
          float z1 = acc[mf][2*p+1][r] + sb[16 + l15];
          float t0 = 1.f - 2.f/(__expf(2.f*z0) + 1.f);   // tanh
          float t1 = 1.f - 2.f/(__expf(2.f*z1) + 1.f);
          float val = t0*w2a + t1*w2b;
          val += __shfl_xor(val, 1); val += __shfl_xor(val, 2);
          val += __shfl_xor(val, 4); val += __shfl_xor(val, 8);
          if (l15 == 0 && rw[r] < N)
            alphaA[(size_t)hh*N + rw[r]] = 1.f/(1.f + __expf(-(val + b2v)));
        }
      }
    }
  }
}

// ---------------- K2a: per-nnz raw attention logits (all heads), written edge-sorted ----------------

__global__ __launch_bounds__(256) void k2a(
    const float* __restrict__ feat, const float* __restrict__ alpha,
    const int* __restrict__ node_idx, const int* __restrict__ edge_idx, const int* __restrict__ edge_type,
    const float* __restrict__ ec,   // [H][ETYPES][HD]
    const int* __restrict__ pos_e,
    float* __restrict__ a_srtE, int NNZ, int N)
{
  int i = blockIdx.x*256 + threadIdx.x;
  if (i >= NNZ) return;
  int n = node_idx[i], e = edge_idx[i];
  int et = edge_type[e];
  int pe = pos_e[i];
  for (int hh = 0; hh < HEADS; hh++){
    const float4* qrow = reinterpret_cast<const float4*>(feat + (size_t)n*256 + hh*HD);
    const float4* crow = reinterpret_cast<const float4*>(ec + (size_t)(hh*ETYPES + et)*HD);
    float s = 0.f;
    #pragma unroll
    for (int k = 0; k < 8; k++){
      float4 q = qrow[k], c = crow[k];
      s += q.x*c.x + q.y*c.y + q.z*c.z + q.w*c.w;
    }
    s = (s >= 0.f) ? s : 0.2f*s;                 // leaky_relu(0.2)
    s *= alpha[(size_t)hh*N + n];
    a_srtE[(size_t)hh*NNZ + pe] = s;
  }
}

// ---------------- K2b: per-(edge,head) wave: segment softmax + edge_feat ----------------

__global__ __launch_bounds__(256) void k2b(
    const float* __restrict__ a_srtE, const int* __restrict__ nidx_srtE,
    const int* __restrict__ edge_off, const int* __restrict__ cnt_e,
    const float* __restrict__ feat, const int* __restrict__ map_e2n,
    float* __restrict__ edge_feat, float* __restrict__ attn_srtN, int NNZ, int N, int E)
{
  int e = blockIdx.x;
  int hh = threadIdx.x >> 6;      // wave id = head
  int lane = threadIdx.x & 63;
  int off = edge_off[e], cnt = cnt_e[e];
  if (cnt == 0) return;

  const float* a = a_srtE + (size_t)hh*NNZ + off;

  float m = -INFINITY;
  for (int j = lane; j < cnt; j += 64) m = fmaxf(m, a[j]);
  #pragma unroll
  for (int s = 32; s > 0; s >>= 1) m = fmaxf(m, __shfl_xor(m, s));

  int p = lane >> 5, d = lane & 31;
  float ef = 0.f, ssum = 0.f;
  for (int jj = 0; jj < cnt; jj += 2){
    int j = jj + p;
    if (j < cnt){
      float ex = __expf(a[j] - m);
      int n = nidx_srtE[off + j];
      ef += ex * feat[(size_t)n*256 + 128 + hh*HD + d];   // V
      ssum += ex;
    }
  }
  ef += __shfl_xor(ef, 32);
  float stot = ssum + __shfl_xor(ssum, 32);
  float inv = 1.0f / stot;
  if (lane < 32) edge_feat[((size_t)hh*E + e)*HD + d] = ef * inv;

  for (int j = lane; j < cnt; j += 64){
    float ex = __expf(a[j] - m);
    attn_srtN[(size_t)hh*NNZ + map_e2n[off + j]] = ex * inv;
  }
}

// ---------------- K2c: per-node block: aggregate + concat heads + residual + LayerNorm ----------------

__global__ __launch_bounds__(128) void k2c(
    const float* __restrict__ attn_srtN, const int* __restrict__ eidx_srtN,
    const int* __restrict__ node_off, const int* __restrict__ cnt_n,
    const float* __restrict__ edge_feat,
    const float* __restrict__ h_in, int hstride,
    const float* __restrict__ ln_g, const float* __restrict__ ln_b,
    float* __restrict__ out, int out_stride, int out_col, int NNZ, int N, int E)
{
  int n = blockIdx.x;
  int t = threadIdx.x;          // 0..127 : head = t>>5, dim = t&31
  int hh = t >> 5, d = t & 31;
  int off = node_off[n], cnt = cnt_n[n];
  const float* attn = attn_srtN + (size_t)hh*NNZ;
  float nf = 0.f;
  for (int j = 0; j < cnt; j++){
    float av = attn[off + j];
    int e = eidx_srtN[off + j];
    nf += av * edge_feat[((size_t)hh*E + e)*HD + d];
  }
  float hn = nf + h_in[(size_t)n*hstride + t];   // residual (IN==HID)

  __shared__ float sred[2];
  float s = hn;
  #pragma unroll
  for (int sh = 32; sh > 0; sh >>= 1) s += __shfl_xor(s, sh);
  if ((t & 63) == 0) sred[t >> 6] = s;
  __syncthreads();
  float mu = (sred[0] + sred[1]) * (1.0f/128.0f);
  __syncthreads();
  float dv = hn - mu;
  float s2 = dv*dv;
  #pragma unroll
  for (int sh = 32; sh > 0; sh >>= 1) s2 += __shfl_xor(s2, sh);
  if ((t & 63) == 0) sred[t >> 6] = s2;
  __syncthreads();
  float var = (sred[0] + sred[1]) * (1.0f/128.0f);
  float r = rsqrtf(var + 1e-5f);
  out[(size_t)n*out_stride + out_col + t] = dv * r * ln_g[t] + ln_b[t];
}

// ---------------- x copy into output columns 0..127 ----------------

__global__ __launch_bounds__(256) void xcopy_k(const float* __restrict__ x, float* __restrict__ out, int N)
{
  int i = blockIdx.x*256 + threadIdx.x;   // over N*32 float4s
  if (i >= N*32) return;
  int n = i >> 5, k = i & 31;
  reinterpret_cast<float4*>(out)[(size_t)n*96 + k] = reinterpret_cast<const float4*>(x)[i];
}

// ---------------- launcher ----------------

extern "C" void kernel_launch(void* const* d_in, const int* in_sizes, int n_in,
                              void* d_out, int out_size, void* d_ws, size_t ws_size,
                              hipStream_t stream)
{
  const float* x          = (const float*)d_in[0];
  const int*   node_types = (const int*)  d_in[1];
  const int*   node_idx   = (const int*)  d_in[2];
  const int*   edge_idx   = (const int*)  d_in[3];
  const int*   edge_type  = (const int*)  d_in[4];
  const float* type_query = (const float*)d_in[5];
  const float* fc1_w      = (const float*)d_in[6];
  const float* fc1_b      = (const float*)d_in[7];
  const float* fc2_w      = (const float*)d_in[8];
  const float* fc2_b      = (const float*)d_in[9];
  const float* Wq         = (const float*)d_in[10];
  const float* Wv         = (const float*)d_in[11];
  const float* edge_ctx   = (const float*)d_in[12];
  const float* ln_g       = (const float*)d_in[13];
  const float* ln_b       = (const float*)d_in[14];

  const int N   = in_sizes[1];
  const int NNZ = in_sizes[2];
  const int E   = in_sizes[4];
  const int L   = 2;

  char* ws = (char*)d_ws;
  size_t o = 0;
  auto alloc = [&](size_t bytes)->void*{
    void* p = ws + o;
    o = (o + bytes + 255) & ~(size_t)255;
    return p;
  };
  int* cnt_e     = (int*)alloc((size_t)E*4);
  int* cur_e     = (int*)alloc((size_t)E*4);
  int* edge_off  = (int*)alloc((size_t)(E+1)*4);
  int* cnt_n     = (int*)alloc((size_t)N*4);
  int* cur_n     = (int*)alloc((size_t)N*4);
  int* node_off  = (int*)alloc((size_t)(N+1)*4);
  int* pos_e     = (int*)alloc((size_t)NNZ*4);
  int* nidx_srtE = (int*)alloc((size_t)NNZ*4);
  int* map_e2n   = (int*)alloc((size_t)NNZ*4);
  int* eidx_srtN = (int*)alloc((size_t)NNZ*4);
  int* bsum      = (int*)alloc((size_t)1024*4);
  float* a_srtE    = (float*)alloc((size_t)HEADS*NNZ*4);
  float* attn_srtN = (float*)alloc((size_t)HEADS*NNZ*4);
  float* feat      = (float*)alloc((size_t)N*256*4);       // [N][256]: Q | V
  float* alphaA    = (float*)alloc((size_t)HEADS*N*4);
  float* edge_featA= (float*)alloc((size_t)HEADS*E*HD*4);
  short* Wt        = (short*)alloc((size_t)L*384*128*2);
  float* sbias     = (float*)alloc((size_t)L*HEADS*NTYPES*32*4);
  if (o > ws_size) return;  // insufficient workspace: bail loudly (output stays wrong)

  hipMemsetAsync(cnt_e, 0, (size_t)E*4, stream);
  hipMemsetAsync(cur_e, 0, (size_t)E*4, stream);
  hipMemsetAsync(cnt_n, 0, (size_t)N*4, stream);
  hipMemsetAsync(cur_n, 0, (size_t)N*4, stream);

  hist_k<<<cdiv(NNZ,256),256,0,stream>>>(node_idx, edge_idx, cnt_e, cnt_n, NNZ);

  int nbE = cdiv(E,1024), nbN = cdiv(N,1024);
  scan_pass1<<<nbE,1024,0,stream>>>(cnt_e, bsum, E);
  scan_pass2<<<1,1024,0,stream>>>(bsum, nbE);
  scan_pass3<<<nbE,1024,0,stream>>>(cnt_e, bsum, edge_off, E);
  scan_pass1<<<nbN,1024,0,stream>>>(cnt_n, bsum, N);
  scan_pass2<<<1,1024,0,stream>>>(bsum, nbN);
  scan_pass3<<<nbN,1024,0,stream>>>(cnt_n, bsum, node_off, N);

  scatter_k<<<cdiv(NNZ,256),256,0,stream>>>(node_idx, edge_idx, edge_off, node_off,
                                            cur_e, cur_n, pos_e, nidx_srtE, map_e2n, eidx_srtN, NNZ);

  wtprep_k<<<L*384,128,0,stream>>>(fc1_w, Wq, Wv, Wt, L);
  sbias_k<<<L*HEADS*NTYPES,32,0,stream>>>(type_query, fc1_w, fc1_b, sbias);

  xcopy_k<<<cdiv(N*32,256),256,0,stream>>>(x, (float*)d_out, N);

  for (int l = 0; l < L; l++){
    const float* hin = (l == 0) ? x : ((const float*)d_out + 128);
    int hstride = (l == 0) ? DIN : (3*DIN);   // 128 or 384

    gemm_k<<<dim3(cdiv(N,128),3),256,0,stream>>>(
        hin, hstride,
        Wt + (size_t)l*384*128,
        node_types,
        sbias + (size_t)l*HEADS*NTYPES*32,
        fc2_w + (size_t)l*HEADS*32,
        fc2_b + (size_t)l*HEADS,
        feat, alphaA, N);

    k2a<<<cdiv(NNZ,256),256,0,stream>>>(feat, alphaA, node_idx, edge_idx, edge_type,
                                        edge_ctx + (size_t)l*HEADS*ETYPES*HD, pos_e,
                                        a_srtE, NNZ, N);

    k2b<<<E,256,0,stream>>>(a_srtE, nidx_srtE, edge_off, cnt_e, feat, map_e2n,
                            edge_featA, attn_srtN, NNZ, N, E);

    k2c<<<N,128,0,stream>>>(attn_srtN, eidx_srtN, node_off, cnt_n, edge_featA,
                            hin, hstride,
                            ln_g + (size_t)l*DIN, ln_b + (size_t)l*DIN,
                            (float*)d_out, 3*DIN, DIN + l*DIN, NNZ, N, E);
  }
}

// Round 4
// 1075.807 us; speedup vs baseline: 2.4644x; 1.1829x over previous
//
#include <hip/hip_runtime.h>
#include <math.h>

#define HEADS 4
#define HD 32      // per-head out dim
#define QD 64      // type query dim
#define DIN 128    // in_dim == hidden_dim
#define NTYPES 4
#define ETYPES 3
#define CAP 512    // per-edge LDS logit capacity (max segment ~85 for this data)

typedef __attribute__((ext_vector_type(8))) short bf16x8;
typedef __attribute__((ext_vector_type(4))) float f32x4;
typedef unsigned short ushort_t;

static inline int cdiv(int a, int b){ return (a + b - 1) / b; }

__device__ inline unsigned short f2bf(float f){
  unsigned u = __float_as_uint(f);
  unsigned r = (u + 0x7FFF + ((u >> 16) & 1)) >> 16;   // RNE
  return (unsigned short)r;
}
__device__ inline float bf2f(unsigned short u){ return __uint_as_float(((unsigned)u) << 16); }

// ---------------- preprocessing: counting sort by edge and by node ----------------

__global__ __launch_bounds__(256) void hist_k(const int* __restrict__ node_idx,
                                              const int* __restrict__ edge_idx,
                                              int* __restrict__ cnt_e, int* __restrict__ cnt_n, int NNZ)
{
  int i = blockIdx.x*256 + threadIdx.x;
  if (i < NNZ){
    atomicAdd(&cnt_e[edge_idx[i]], 1);
    atomicAdd(&cnt_n[node_idx[i]], 1);
  }
}

__global__ __launch_bounds__(1024) void scan_pass1(const int* __restrict__ in, int* __restrict__ bsums, int n)
{
  __shared__ int sd[1024];
  int i = blockIdx.x*1024 + threadIdx.x;
  sd[threadIdx.x] = (i < n) ? in[i] : 0;
  __syncthreads();
  for (int s = 512; s > 0; s >>= 1){
    if (threadIdx.x < s) sd[threadIdx.x] += sd[threadIdx.x + s];
    __syncthreads();
  }
  if (threadIdx.x == 0) bsums[blockIdx.x] = sd[0];
}

__global__ __launch_bounds__(1024) void scan_pass2(int* __restrict__ bsums, int nb)
{
  __shared__ int sd[1024];
  int v = (threadIdx.x < nb) ? bsums[threadIdx.x] : 0;
  sd[threadIdx.x] = v;
  __syncthreads();
  for (int s = 1; s < 1024; s <<= 1){
    int t = (threadIdx.x >= s) ? sd[threadIdx.x - s] : 0;
    __syncthreads();
    sd[threadIdx.x] += t;
    __syncthreads();
  }
  if (threadIdx.x < nb) bsums[threadIdx.x] = sd[threadIdx.x] - v;  // exclusive
}

__global__ __launch_bounds__(1024) void scan_pass3(const int* __restrict__ in, const int* __restrict__ bsums,
                                                   int* __restrict__ out, int n)
{
  __shared__ int sd[1024];
  int i = blockIdx.x*1024 + threadIdx.x;
  int v = (i < n) ? in[i] : 0;
  sd[threadIdx.x] = v;
  __syncthreads();
  for (int s = 1; s < 1024; s <<= 1){
    int t = (threadIdx.x >= s) ? sd[threadIdx.x - s] : 0;
    __syncthreads();
    sd[threadIdx.x] += t;
    __syncthreads();
  }
  if (i < n) out[i] = bsums[blockIdx.x] + sd[threadIdx.x] - v;  // exclusive offsets
}

__global__ __launch_bounds__(256) void scatter_k(const int* __restrict__ node_idx, const int* __restrict__ edge_idx,
                                                 const int* __restrict__ edge_off, const int* __restrict__ node_off,
                                                 int* __restrict__ cur_e, int* __restrict__ cur_n,
                                                 int* __restrict__ nidx_srtE,
                                                 int* __restrict__ map_e2n, int* __restrict__ eidx_srtN, int NNZ)
{
  int i = blockIdx.x*256 + threadIdx.x;
  if (i >= NNZ) return;
  int n = node_idx[i], e = edge_idx[i];
  int pe = edge_off[e] + atomicAdd(&cur_e[e], 1);
  int pn = node_off[n] + atomicAdd(&cur_n[n], 1);
  nidx_srtE[pe] = n;
  eidx_srtN[pn] = e;
  map_e2n[pe]   = pn;
}

// ---------------- weight prep: Wt[384][128] bf16, sbias ----------------

// Wt col layout: c in [0,128): fc1 (hh=c>>5, j=c&31); [128,256): Wq; [256,384): Wv
__global__ __launch_bounds__(128) void wtprep_k(const float* __restrict__ w1, const float* __restrict__ wq,
                                                const float* __restrict__ wv, short* __restrict__ Wt, int L)
{
  int c = blockIdx.x % 384, l = blockIdx.x / 384;
  int k = threadIdx.x;
  int sec = c >> 7;
  int hh = (c >> 5) & 3, j = c & 31;
  float v;
  if (sec == 0)      v = w1[((((size_t)l*HEADS + hh)*(DIN+QD)) + k)*32 + j];
  else if (sec == 1) v = wq[((((size_t)l*HEADS + hh)*DIN) + k)*32 + j];
  else               v = wv[((((size_t)l*HEADS + hh)*DIN) + k)*32 + j];
  Wt[((size_t)l*384 + c)*128 + k] = (short)f2bf(v);
}

// sbias[l][hh][ty][j] = b1 + sig @ w1[128:192]
__global__ __launch_bounds__(32) void sbias_k(const float* __restrict__ tq, const float* __restrict__ w1,
                                              const float* __restrict__ b1, float* __restrict__ sbias)
{
  int b = blockIdx.x;
  int ty = b % NTYPES; int hh = (b / NTYPES) % HEADS; int l = b / (NTYPES*HEADS);
  int j = threadIdx.x;
  const float* tqp = tq + (((size_t)l*HEADS + hh)*NTYPES + ty)*QD;
  const float* w1p = w1 + ((size_t)l*HEADS + hh)*(DIN+QD)*32;
  float s = b1[((size_t)l*HEADS + hh)*32 + j];
  for (int k = 0; k < QD; k++) s += tqp[k] * w1p[(size_t)(DIN + k)*32 + j];
  sbias[(size_t)b*32 + j] = s;
}

// ---------------- shared A-fragment loader for both GEMMs ----------------

__device__ inline void load_afrag(const float* __restrict__ h, int hstride, int N,
                                  int rbase, int mf, int l15, int l4, int kk, bf16x8& a)
{
  int row = rbase + mf*16 + l15;
  int rr = (row < N) ? row : (N-1);
  const float* pa = h + (size_t)rr*hstride + kk*32 + l4*8;
  float4 f0 = *(const float4*)pa;
  float4 f1 = *(const float4*)(pa + 4);
  a[0] = (short)f2bf(f0.x); a[1] = (short)f2bf(f0.y);
  a[2] = (short)f2bf(f0.z); a[3] = (short)f2bf(f0.w);
  a[4] = (short)f2bf(f1.x); a[5] = (short)f2bf(f1.y);
  a[6] = (short)f2bf(f1.z); a[7] = (short)f2bf(f1.w);
}

// ---------------- gemmA: h @ W_fc1 -> tanh -> fc2 -> sigmoid -> alphaA[H][N] ----------------

__global__ __launch_bounds__(256) void gemma_k(
    const float* __restrict__ h, int hstride,
    const short* __restrict__ Wt,          // this layer, cols 0..127 used
    const int* __restrict__ node_types,
    const float* __restrict__ sbias,       // [H][NTYPES][32]
    const float* __restrict__ w2,          // [H][32]
    const float* __restrict__ b2,          // [H]
    float* __restrict__ alphaA,            // [H][N]
    int N)
{
  int lane = threadIdx.x & 63, wv = threadIdx.x >> 6;
  int wr = wv >> 1, wc = wv & 1;
  int l15 = lane & 15, l4 = lane >> 4;
  int rbase = blockIdx.x*128 + wr*64;

  f32x4 acc[4][4] = {};

  #pragma unroll
  for (int kk = 0; kk < 4; kk++){
    bf16x8 a[4], b[4];
    #pragma unroll
    for (int mf = 0; mf < 4; mf++) load_afrag(h, hstride, N, rbase, mf, l15, l4, kk, a[mf]);
    #pragma unroll
    for (int cf = 0; cf < 4; cf++){
      int col = wc*64 + cf*16 + l15;
      b[cf] = *(const bf16x8*)(Wt + (size_t)col*128 + kk*32 + l4*8);
    }
    #pragma unroll
    for (int mf = 0; mf < 4; mf++)
      #pragma unroll
      for (int cf = 0; cf < 4; cf++)
        acc[mf][cf] = __builtin_amdgcn_mfma_f32_16x16x32_bf16(a[mf], b[cf], acc[mf][cf], 0, 0, 0);
  }

  #pragma unroll
  for (int mf = 0; mf < 4; mf++){
    int rw[4], ty[4];
    #pragma unroll
    for (int r = 0; r < 4; r++){
      rw[r] = rbase + mf*16 + l4*4 + r;
      ty[r] = (rw[r] < N) ? node_types[rw[r]] : 0;
    }
    #pragma unroll
    for (int p = 0; p < 2; p++){
      int hh = wc*2 + p;
      float w2a = w2[hh*32 + l15];
      float w2b = w2[hh*32 + 16 + l15];
      float b2v = b2[hh];
      #pragma unroll
      for (int r = 0; r < 4; r++){
        const float* sb = sbias + ((size_t)hh*NTYPES + ty[r])*32;
        float z0 = acc[mf][2*p  ][r] + sb[l15];
        float z1 = acc[mf][2*p+1][r] + sb[16 + l15];
        float t0 = 1.f - 2.f/(__expf(2.f*z0) + 1.f);   // tanh
        float t1 = 1.f - 2.f/(__expf(2.f*z1) + 1.f);
        float val = t0*w2a + t1*w2b;
        val += __shfl_xor(val, 1); val += __shfl_xor(val, 2);
        val += __shfl_xor(val, 4); val += __shfl_xor(val, 8);
        if (l15 == 0 && rw[r] < N)
          alphaA[(size_t)hh*N + rw[r]] = 1.f/(1.f + __expf(-(val + b2v)));
      }
    }
  }
}

// ---------------- gemmQV: h @ [Wq|Wv] -> qv[h][n][64] bf16 (Q pre-scaled by alpha) ----------------
// blockIdx.y: 0 -> Q (Wt cols 128..255), 1 -> V (cols 256..383)

__global__ __launch_bounds__(256) void gemmqv_k(
    const float* __restrict__ h, int hstride,
    const short* __restrict__ Wt,
    const float* __restrict__ alphaA,
    ushort_t* __restrict__ qv,             // [H][N][64]: Q(32) | V(32)
    int N)
{
  int lane = threadIdx.x & 63, wv = threadIdx.x >> 6;
  int wr = wv >> 1, wc = wv & 1;
  int l15 = lane & 15, l4 = lane >> 4;
  int rbase = blockIdx.x*128 + wr*64;
  int ct = blockIdx.y;          // 0=Q, 1=V

  f32x4 acc[4][4] = {};

  #pragma unroll
  for (int kk = 0; kk < 4; kk++){
    bf16x8 a[4], b[4];
    #pragma unroll
    for (int mf = 0; mf < 4; mf++) load_afrag(h, hstride, N, rbase, mf, l15, l4, kk, a[mf]);
    #pragma unroll
    for (int cf = 0; cf < 4; cf++){
      int col = 128 + ct*128 + wc*64 + cf*16 + l15;
      b[cf] = *(const bf16x8*)(Wt + (size_t)col*128 + kk*32 + l4*8);
    }
    #pragma unroll
    for (int mf = 0; mf < 4; mf++)
      #pragma unroll
      for (int cf = 0; cf < 4; cf++)
        acc[mf][cf] = __builtin_amdgcn_mfma_f32_16x16x32_bf16(a[mf], b[cf], acc[mf][cf], 0, 0, 0);
  }

  #pragma unroll
  for (int mf = 0; mf < 4; mf++){
    #pragma unroll
    for (int r = 0; r < 4; r++){
      int row = rbase + mf*16 + l4*4 + r;
      if (row < N){
        #pragma unroll
        for (int cf = 0; cf < 4; cf++){
          int c = wc*64 + cf*16 + l15;        // 0..127
          int hh = c >> 5, d = c & 31;
          float val = acc[mf][cf][r];
          if (ct == 0) val *= alphaA[(size_t)hh*N + row];
          qv[((size_t)hh*N + row)*64 + ct*32 + d] = f2bf(val);
        }
      }
    }
  }
}

// ---------------- k2b fused: logits + segment softmax + edge_feat + packed attn ----------------
// grid E, 4 waves (one per head). Quarter-wave (16 lanes) per entry; lane g handles dims 2g,2g+1.

__global__ __launch_bounds__(256) void k2b_f(
    const ushort_t* __restrict__ qv,
    const int* __restrict__ nidx_srtE, const int* __restrict__ edge_off, const int* __restrict__ cnt_e,
    const int* __restrict__ edge_type, const float* __restrict__ ec,   // [H][ETYPES][32]
    const int* __restrict__ map_e2n,
    ushort_t* __restrict__ efb,            // [H][E][32] bf16
    ushort_t* __restrict__ attn_pk,        // [NNZ][4] bf16 (node-sorted positions)
    int N, int E)
{
  __shared__ float lbuf[HEADS][CAP];
  __shared__ float mi[HEADS][2];

  int e = blockIdx.x;
  int off = edge_off[e], cnt = cnt_e[e];
  if (cnt == 0) return;
  int lane = threadIdx.x & 63, hh = threadIdx.x >> 6;
  int g = lane & 15, grp = lane >> 4;
  int et = edge_type[e];
  float2 cv = *(const float2*)&ec[(size_t)(hh*ETYPES + et)*32 + 2*g];
  const ushort_t* qvh = qv + (size_t)hh*N*64;

  if (cnt <= CAP){
    // phase A: logits -> LDS, running max
    float mloc = -INFINITY;
    for (int jj = 0; jj < cnt; jj += 4){
      int j = jj + grp;
      float s = -INFINITY;
      if (j < cnt){
        unsigned qw = *(const unsigned*)&qvh[(size_t)nidx_srtE[off + j]*64 + 2*g];
        s = bf2f((unsigned short)(qw & 0xffff))*cv.x + bf2f((unsigned short)(qw >> 16))*cv.y;
      }
      s += __shfl_xor(s, 1); s += __shfl_xor(s, 2); s += __shfl_xor(s, 4); s += __shfl_xor(s, 8);
      if (j < cnt){
        s = (s >= 0.f) ? s : 0.2f*s;
        if (g == 0) lbuf[hh][j] = s;
        mloc = fmaxf(mloc, s);
      }
    }
    mloc = fmaxf(mloc, __shfl_xor(mloc, 16));
    mloc = fmaxf(mloc, __shfl_xor(mloc, 32));
    float m = mloc;

    // phase B: exp-sum + V accumulate
    float ef0 = 0.f, ef1 = 0.f, ssum = 0.f;
    for (int jj = 0; jj < cnt; jj += 4){
      int j = jj + grp;
      if (j < cnt){
        float ex = __expf(lbuf[hh][j] - m);
        unsigned vw = *(const unsigned*)&qvh[(size_t)nidx_srtE[off + j]*64 + 32 + 2*g];
        ef0 += ex * bf2f((unsigned short)(vw & 0xffff));
        ef1 += ex * bf2f((unsigned short)(vw >> 16));
        ssum += ex;
      }
    }
    ef0 += __shfl_xor(ef0, 16); ef0 += __shfl_xor(ef0, 32);
    ef1 += __shfl_xor(ef1, 16); ef1 += __shfl_xor(ef1, 32);
    ssum += __shfl_xor(ssum, 16); ssum += __shfl_xor(ssum, 32);
    float inv = 1.0f / ssum;
    if (grp == 0){
      unsigned w = (unsigned)f2bf(ef0*inv) | ((unsigned)f2bf(ef1*inv) << 16);
      *(unsigned*)&efb[((size_t)hh*E + e)*32 + 2*g] = w;
    }
    if (lane == 0){ mi[hh][0] = m; mi[hh][1] = inv; }
    __syncthreads();

    // phase C: wave 0 packs 4 heads' attn, one 8B scattered store per entry
    if (hh == 0){
      for (int j = lane; j < cnt; j += 64){
        int pn = map_e2n[off + j];
        float a0 = __expf(lbuf[0][j] - mi[0][0]) * mi[0][1];
        float a1 = __expf(lbuf[1][j] - mi[1][0]) * mi[1][1];
        float a2 = __expf(lbuf[2][j] - mi[2][0]) * mi[2][1];
        float a3 = __expf(lbuf[3][j] - mi[3][0]) * mi[3][1];
        uint2 o;
        o.x = (unsigned)f2bf(a0) | ((unsigned)f2bf(a1) << 16);
        o.y = (unsigned)f2bf(a2) | ((unsigned)f2bf(a3) << 16);
        *(uint2*)&attn_pk[(size_t)pn*4] = o;
      }
    }
  } else {
    // slow path (cnt > CAP): never taken for this data; recompute logits per pass
    float mloc = -INFINITY;
    for (int jj = 0; jj < cnt; jj += 4){
      int j = jj + grp;
      float s = -INFINITY;
      if (j < cnt){
        unsigned qw = *(const unsigned*)&qvh[(size_t)nidx_srtE[off + j]*64 + 2*g];
        s = bf2f((unsigned short)(qw & 0xffff))*cv.x + bf2f((unsigned short)(qw >> 16))*cv.y;
      }
      s += __shfl_xor(s, 1); s += __shfl_xor(s, 2); s += __shfl_xor(s, 4); s += __shfl_xor(s, 8);
      if (j < cnt) mloc = fmaxf(mloc, (s >= 0.f) ? s : 0.2f*s);
    }
    mloc = fmaxf(mloc, __shfl_xor(mloc, 16));
    mloc = fmaxf(mloc, __shfl_xor(mloc, 32));
    float m = mloc;

    float ef0 = 0.f, ef1 = 0.f, ssum = 0.f;
    for (int jj = 0; jj < cnt; jj += 4){
      int j = jj + grp;
      float s = -INFINITY; int n = 0;
      if (j < cnt){
        n = nidx_srtE[off + j];
        unsigned qw = *(const unsigned*)&qvh[(size_t)n*64 + 2*g];
        s = bf2f((unsigned short)(qw & 0xffff))*cv.x + bf2f((unsigned short)(qw >> 16))*cv.y;
      }
      s += __shfl_xor(s, 1); s += __shfl_xor(s, 2); s += __shfl_xor(s, 4); s += __shfl_xor(s, 8);
      if (j < cnt){
        s = (s >= 0.f) ? s : 0.2f*s;
        float ex = __expf(s - m);
        unsigned vw = *(const unsigned*)&qvh[(size_t)n*64 + 32 + 2*g];
        ef0 += ex * bf2f((unsigned short)(vw & 0xffff));
        ef1 += ex * bf2f((unsigned short)(vw >> 16));
        ssum += ex;
      }
    }
    ef0 += __shfl_xor(ef0, 16); ef0 += __shfl_xor(ef0, 32);
    ef1 += __shfl_xor(ef1, 16); ef1 += __shfl_xor(ef1, 32);
    ssum += __shfl_xor(ssum, 16); ssum += __shfl_xor(ssum, 32);
    float inv = 1.0f / ssum;
    if (grp == 0){
      unsigned w = (unsigned)f2bf(ef0*inv) | ((unsigned)f2bf(ef1*inv) << 16);
      *(unsigned*)&efb[((size_t)hh*E + e)*32 + 2*g] = w;
    }
    for (int jj = 0; jj < cnt; jj += 4){
      int j = jj + grp;
      float s = -INFINITY; int pn = 0;
      if (j < cnt){
        int n = nidx_srtE[off + j];
        pn = map_e2n[off + j];
        unsigned qw = *(const unsigned*)&qvh[(size_t)n*64 + 2*g];
        s = bf2f((unsigned short)(qw & 0xffff))*cv.x + bf2f((unsigned short)(qw >> 16))*cv.y;
      }
      s += __shfl_xor(s, 1); s += __shfl_xor(s, 2); s += __shfl_xor(s, 4); s += __shfl_xor(s, 8);
      if (j < cnt && g == 0){
        s = (s >= 0.f) ? s : 0.2f*s;
        attn_pk[(size_t)pn*4 + hh] = f2bf(__expf(s - m) * inv);
      }
    }
  }
}

// ---------------- K2c: per-node block: aggregate + concat heads + residual + LayerNorm ----------------

__global__ __launch_bounds__(128) void k2c(
    const ushort_t* __restrict__ attn_pk, const int* __restrict__ eidx_srtN,
    const int* __restrict__ node_off, const int* __restrict__ cnt_n,
    const ushort_t* __restrict__ efb,
    const float* __restrict__ h_in, int hstride,
    const float* __restrict__ ln_g, const float* __restrict__ ln_b,
    float* __restrict__ out, int out_stride, int out_col, int N, int E)
{
  int n = blockIdx.x;
  int t = threadIdx.x;          // 0..127 : head = t>>5, dim = t&31
  int hh = t >> 5, d = t & 31;
  int off = node_off[n], cnt = cnt_n[n];
  float nf = 0.f;
  for (int j = 0; j < cnt; j++){
    int e = eidx_srtN[off + j];
    uint2 ap = *(const uint2*)&attn_pk[(size_t)(off + j)*4];
    unsigned u = (hh & 2) ? ap.y : ap.x;
    unsigned short us = (hh & 1) ? (unsigned short)(u >> 16) : (unsigned short)(u & 0xffff);
    float av = bf2f(us);
    float ev = bf2f(efb[((size_t)hh*E + e)*32 + d]);
    nf += av * ev;
  }
  float hn = nf + h_in[(size_t)n*hstride + t];   // residual (IN==HID)

  __shared__ float sred[2];
  float s = hn;
  #pragma unroll
  for (int sh = 32; sh > 0; sh >>= 1) s += __shfl_xor(s, sh);
  if ((t & 63) == 0) sred[t >> 6] = s;
  __syncthreads();
  float mu = (sred[0] + sred[1]) * (1.0f/128.0f);
  __syncthreads();
  float dv = hn - mu;
  float s2 = dv*dv;
  #pragma unroll
  for (int sh = 32; sh > 0; sh >>= 1) s2 += __shfl_xor(s2, sh);
  if ((t & 63) == 0) sred[t >> 6] = s2;
  __syncthreads();
  float var = (sred[0] + sred[1]) * (1.0f/128.0f);
  float r = rsqrtf(var + 1e-5f);
  out[(size_t)n*out_stride + out_col + t] = dv * r * ln_g[t] + ln_b[t];
}

// ---------------- x copy into output columns 0..127 ----------------

__global__ __launch_bounds__(256) void xcopy_k(const float* __restrict__ x, float* __restrict__ out, int N)
{
  int i = blockIdx.x*256 + threadIdx.x;   // over N*32 float4s
  if (i >= N*32) return;
  int n = i >> 5, k = i & 31;
  reinterpret_cast<float4*>(out)[(size_t)n*96 + k] = reinterpret_cast<const float4*>(x)[i];
}

// ---------------- launcher ----------------

extern "C" void kernel_launch(void* const* d_in, const int* in_sizes, int n_in,
                              void* d_out, int out_size, void* d_ws, size_t ws_size,
                              hipStream_t stream)
{
  const float* x          = (const float*)d_in[0];
  const int*   node_types = (const int*)  d_in[1];
  const int*   node_idx   = (const int*)  d_in[2];
  const int*   edge_idx   = (const int*)  d_in[3];
  const int*   edge_type  = (const int*)  d_in[4];
  const float* type_query = (const float*)d_in[5];
  const float* fc1_w      = (const float*)d_in[6];
  const float* fc1_b      = (const float*)d_in[7];
  const float* fc2_w      = (const float*)d_in[8];
  const float* fc2_b      = (const float*)d_in[9];
  const float* Wq         = (const float*)d_in[10];
  const float* Wv         = (const float*)d_in[11];
  const float* edge_ctx   = (const float*)d_in[12];
  const float* ln_g       = (const float*)d_in[13];
  const float* ln_b       = (const float*)d_in[14];

  const int N   = in_sizes[1];
  const int NNZ = in_sizes[2];
  const int E   = in_sizes[4];
  const int L   = 2;

  char* ws = (char*)d_ws;
  size_t o = 0;
  auto alloc = [&](size_t bytes)->void*{
    void* p = ws + o;
    o = (o + bytes + 255) & ~(size_t)255;
    return p;
  };
  int* cnt_e     = (int*)alloc((size_t)E*4);
  int* cur_e     = (int*)alloc((size_t)E*4);
  int* edge_off  = (int*)alloc((size_t)(E+1)*4);
  int* cnt_n     = (int*)alloc((size_t)N*4);
  int* cur_n     = (int*)alloc((size_t)N*4);
  int* node_off  = (int*)alloc((size_t)(N+1)*4);
  int* nidx_srtE = (int*)alloc((size_t)NNZ*4);
  int* map_e2n   = (int*)alloc((size_t)NNZ*4);
  int* eidx_srtN = (int*)alloc((size_t)NNZ*4);
  int* bsum      = (int*)alloc((size_t)1024*4);
  ushort_t* attn_pk = (ushort_t*)alloc((size_t)NNZ*4*2);          // [NNZ][4] bf16
  ushort_t* qv      = (ushort_t*)alloc((size_t)HEADS*N*64*2);     // [H][N][64] bf16
  float*    alphaA  = (float*)alloc((size_t)HEADS*N*4);
  ushort_t* efb     = (ushort_t*)alloc((size_t)HEADS*E*32*2);     // [H][E][32] bf16
  short*    Wt      = (short*)alloc((size_t)L*384*128*2);
  float*    sbias   = (float*)alloc((size_t)L*HEADS*NTYPES*32*4);
  if (o > ws_size) return;  // insufficient workspace: bail loudly (output stays wrong)

  hipMemsetAsync(cnt_e, 0, (size_t)E*4, stream);
  hipMemsetAsync(cur_e, 0, (size_t)E*4, stream);
  hipMemsetAsync(cnt_n, 0, (size_t)N*4, stream);
  hipMemsetAsync(cur_n, 0, (size_t)N*4, stream);

  hist_k<<<cdiv(NNZ,256),256,0,stream>>>(node_idx, edge_idx, cnt_e, cnt_n, NNZ);

  int nbE = cdiv(E,1024), nbN = cdiv(N,1024);
  scan_pass1<<<nbE,1024,0,stream>>>(cnt_e, bsum, E);
  scan_pass2<<<1,1024,0,stream>>>(bsum, nbE);
  scan_pass3<<<nbE,1024,0,stream>>>(cnt_e, bsum, edge_off, E);
  scan_pass1<<<nbN,1024,0,stream>>>(cnt_n, bsum, N);
  scan_pass2<<<1,1024,0,stream>>>(bsum, nbN);
  scan_pass3<<<nbN,1024,0,stream>>>(cnt_n, bsum, node_off, N);

  scatter_k<<<cdiv(NNZ,256),256,0,stream>>>(node_idx, edge_idx, edge_off, node_off,
                                            cur_e, cur_n, nidx_srtE, map_e2n, eidx_srtN, NNZ);

  wtprep_k<<<L*384,128,0,stream>>>(fc1_w, Wq, Wv, Wt, L);
  sbias_k<<<L*HEADS*NTYPES,32,0,stream>>>(type_query, fc1_w, fc1_b, sbias);

  xcopy_k<<<cdiv(N*32,256),256,0,stream>>>(x, (float*)d_out, N);

  for (int l = 0; l < L; l++){
    const float* hin = (l == 0) ? x : ((const float*)d_out + 128);
    int hstride = (l == 0) ? DIN : (3*DIN);   // 128 or 384

    gemma_k<<<cdiv(N,128),256,0,stream>>>(
        hin, hstride,
        Wt + (size_t)l*384*128,
        node_types,
        sbias + (size_t)l*HEADS*NTYPES*32,
        fc2_w + (size_t)l*HEADS*32,
        fc2_b + (size_t)l*HEADS,
        alphaA, N);

    gemmqv_k<<<dim3(cdiv(N,128),2),256,0,stream>>>(
        hin, hstride,
        Wt + (size_t)l*384*128,
        alphaA, qv, N);

    k2b_f<<<E,256,0,stream>>>(qv, nidx_srtE, edge_off, cnt_e,
                              edge_type, edge_ctx + (size_t)l*HEADS*ETYPES*HD,
                              map_e2n, efb, attn_pk, N, E);

    k2c<<<N,128,0,stream>>>(attn_pk, eidx_srtN, node_off, cnt_n, efb,
                            hin, hstride,
                            ln_g + (size_t)l*DIN, ln_b + (size_t)l*DIN,
                            (float*)d_out, 3*DIN, DIN + l*DIN, N, E);
  }
}

// Round 5
// 848.836 us; speedup vs baseline: 3.1233x; 1.2674x over previous
//
#include <hip/hip_runtime.h>
#include <math.h>

#define HEADS 4
#define HD 32      // per-head out dim
#define QD 64      // type query dim
#define DIN 128    // in_dim == hidden_dim
#define NTYPES 4
#define ETYPES 3
#define CAP 512    // per-edge LDS logit capacity (max segment ~85 for this data)
#define WTC 272    // Wt columns per layer: 0..127 fc1, 128..255 Wv, 256..267 Wqc(logit)

typedef __attribute__((ext_vector_type(8))) short bf16x8;
typedef __attribute__((ext_vector_type(4))) float f32x4;
typedef unsigned short ushort_t;

static inline int cdiv(int a, int b){ return (a + b - 1) / b; }

__device__ inline unsigned short f2bf(float f){
  unsigned u = __float_as_uint(f);
  unsigned r = (u + 0x7FFF + ((u >> 16) & 1)) >> 16;   // RNE
  return (unsigned short)r;
}
__device__ inline float bf2f(unsigned short u){ return __uint_as_float(((unsigned)u) << 16); }

// lgt layout: [n][et][h] bf16, row = 12 ushorts = 24B; one uint2 = all 4 heads of (n,et)
__device__ inline float lgt_get(const ushort_t* __restrict__ lgt, int n, int et, int hh){
  uint2 lg = *(const uint2*)((const char*)lgt + (size_t)n*24 + et*8);
  unsigned u = (hh & 2) ? lg.y : lg.x;
  return bf2f((hh & 1) ? (ushort_t)(u >> 16) : (ushort_t)(u & 0xffff));
}

// ---------------- preprocessing: counting sort by edge and by node ----------------

__global__ __launch_bounds__(256) void hist_k(const int* __restrict__ node_idx,
                                              const int* __restrict__ edge_idx,
                                              int* __restrict__ cnt_e, int* __restrict__ cnt_n, int NNZ)
{
  int i = blockIdx.x*256 + threadIdx.x;
  if (i < NNZ){
    atomicAdd(&cnt_e[edge_idx[i]], 1);
    atomicAdd(&cnt_n[node_idx[i]], 1);
  }
}

__global__ __launch_bounds__(1024) void scan_pass1(const int* __restrict__ in, int* __restrict__ bsums, int n)
{
  __shared__ int sd[1024];
  int i = blockIdx.x*1024 + threadIdx.x;
  sd[threadIdx.x] = (i < n) ? in[i] : 0;
  __syncthreads();
  for (int s = 512; s > 0; s >>= 1){
    if (threadIdx.x < s) sd[threadIdx.x] += sd[threadIdx.x + s];
    __syncthreads();
  }
  if (threadIdx.x == 0) bsums[blockIdx.x] = sd[0];
}

__global__ __launch_bounds__(1024) void scan_pass2(int* __restrict__ bsums, int nb)
{
  __shared__ int sd[1024];
  int v = (threadIdx.x < nb) ? bsums[threadIdx.x] : 0;
  sd[threadIdx.x] = v;
  __syncthreads();
  for (int s = 1; s < 1024; s <<= 1){
    int t = (threadIdx.x >= s) ? sd[threadIdx.x - s] : 0;
    __syncthreads();
    sd[threadIdx.x] += t;
    __syncthreads();
  }
  if (threadIdx.x < nb) bsums[threadIdx.x] = sd[threadIdx.x] - v;  // exclusive
}

__global__ __launch_bounds__(1024) void scan_pass3(const int* __restrict__ in, const int* __restrict__ bsums,
                                                   int* __restrict__ out, int n)
{
  __shared__ int sd[1024];
  int i = blockIdx.x*1024 + threadIdx.x;
  int v = (i < n) ? in[i] : 0;
  sd[threadIdx.x] = v;
  __syncthreads();
  for (int s = 1; s < 1024; s <<= 1){
    int t = (threadIdx.x >= s) ? sd[threadIdx.x - s] : 0;
    __syncthreads();
    sd[threadIdx.x] += t;
    __syncthreads();
  }
  if (i < n) out[i] = bsums[blockIdx.x] + sd[threadIdx.x] - v;  // exclusive offsets
}

__global__ __launch_bounds__(256) void scatter_k(const int* __restrict__ node_idx, const int* __restrict__ edge_idx,
                                                 const int* __restrict__ edge_off, const int* __restrict__ node_off,
                                                 int* __restrict__ cur_e, int* __restrict__ cur_n,
                                                 int* __restrict__ nidx_srtE,
                                                 int* __restrict__ map_e2n, int* __restrict__ eidx_srtN, int NNZ)
{
  int i = blockIdx.x*256 + threadIdx.x;
  if (i >= NNZ) return;
  int n = node_idx[i], e = edge_idx[i];
  int pe = edge_off[e] + atomicAdd(&cur_e[e], 1);
  int pn = node_off[n] + atomicAdd(&cur_n[n], 1);
  nidx_srtE[pe] = n;
  eidx_srtN[pn] = e;
  map_e2n[pe]   = pn;
}

// ---------------- weight prep ----------------

// Wt cols 0..127: fc1 (hh=c>>5, j=c&31); 128..255: Wv
__global__ __launch_bounds__(128) void wtprep_k(const float* __restrict__ w1, const float* __restrict__ wv,
                                                short* __restrict__ Wt, int L)
{
  int c = blockIdx.x % 256, l = blockIdx.x / 256;
  int k = threadIdx.x;
  int hh = (c >> 5) & 3, j = c & 31;
  float v;
  if (c < 128) v = w1[((((size_t)l*HEADS + hh)*(DIN+QD)) + k)*32 + j];
  else         v = wv[((((size_t)l*HEADS + hh)*DIN) + k)*32 + j];
  Wt[((size_t)l*WTC + c)*128 + k] = (short)f2bf(v);
}

// Wqc logit columns: Wt[l][256 + h*3+et][k] = sum_d wq[l][h][k][d] * ec[l][h][et][d]
__global__ __launch_bounds__(128) void wqc_k(const float* __restrict__ wq, const float* __restrict__ ec,
                                             short* __restrict__ Wt)
{
  int b = blockIdx.x;                 // l*12 + h*3 + et
  int l = b / 12, c = b % 12, h = c / 3, et = c % 3;
  int k = threadIdx.x;
  const float* wrow = wq + ((((size_t)l*HEADS + h)*DIN) + k)*32;
  const float* ecp  = ec + (((size_t)l*HEADS + h)*ETYPES + et)*32;
  float s = 0.f;
  #pragma unroll
  for (int d = 0; d < 32; d++) s += wrow[d] * ecp[d];
  Wt[((size_t)l*WTC + 256 + c)*128 + k] = (short)f2bf(s);
}

// sbias[l][hh][ty][j] = b1 + sig @ w1[128:192]
__global__ __launch_bounds__(32) void sbias_k(const float* __restrict__ tq, const float* __restrict__ w1,
                                              const float* __restrict__ b1, float* __restrict__ sbias)
{
  int b = blockIdx.x;
  int ty = b % NTYPES; int hh = (b / NTYPES) % HEADS; int l = b / (NTYPES*HEADS);
  int j = threadIdx.x;
  const float* tqp = tq + (((size_t)l*HEADS + hh)*NTYPES + ty)*QD;
  const float* w1p = w1 + ((size_t)l*HEADS + hh)*(DIN+QD)*32;
  float s = b1[((size_t)l*HEADS + hh)*32 + j];
  for (int k = 0; k < QD; k++) s += tqp[k] * w1p[(size_t)(DIN + k)*32 + j];
  sbias[(size_t)b*32 + j] = s;
}

// ---------------- shared A-fragment loader ----------------

__device__ inline void load_afrag(const float* __restrict__ h, int hstride, int N,
                                  int rbase, int mf, int l15, int l4, int kk, bf16x8& a)
{
  int row = rbase + mf*16 + l15;
  int rr = (row < N) ? row : (N-1);
  const float* pa = h + (size_t)rr*hstride + kk*32 + l4*8;
  float4 f0 = *(const float4*)pa;
  float4 f1 = *(const float4*)(pa + 4);
  a[0] = (short)f2bf(f0.x); a[1] = (short)f2bf(f0.y);
  a[2] = (short)f2bf(f0.z); a[3] = (short)f2bf(f0.w);
  a[4] = (short)f2bf(f1.x); a[5] = (short)f2bf(f1.y);
  a[6] = (short)f2bf(f1.z); a[7] = (short)f2bf(f1.w);
}

// ---------------- gemmA: fc1 -> alpha (LDS) + fused logit columns -> lgt ----------------

__global__ __launch_bounds__(256) void gemma_k(
    const float* __restrict__ h, int hstride,
    const short* __restrict__ Wt,          // this layer
    const int* __restrict__ node_types,
    const float* __restrict__ sbias,       // [H][NTYPES][32]
    const float* __restrict__ w2,          // [H][32]
    const float* __restrict__ b2,          // [H]
    ushort_t* __restrict__ lgt,            // [N][ET][H] bf16
    int N)
{
  __shared__ float alds[128][HEADS];
  int lane = threadIdx.x & 63, wvid = threadIdx.x >> 6;
  int wr = wvid >> 1, wc = wvid & 1;
  int l15 = lane & 15, l4 = lane >> 4;
  int rbase = blockIdx.x*128 + wr*64;

  f32x4 acc[4][4] = {};
  f32x4 acc_e[4] = {};

  #pragma unroll
  for (int kk = 0; kk < 4; kk++){
    bf16x8 a[4], b[4];
    #pragma unroll
    for (int mf = 0; mf < 4; mf++) load_afrag(h, hstride, N, rbase, mf, l15, l4, kk, a[mf]);
    #pragma unroll
    for (int cf = 0; cf < 4; cf++){
      int col = wc*64 + cf*16 + l15;
      b[cf] = *(const bf16x8*)(Wt + (size_t)col*128 + kk*32 + l4*8);
    }
    #pragma unroll
    for (int mf = 0; mf < 4; mf++)
      #pragma unroll
      for (int cf = 0; cf < 4; cf++)
        acc[mf][cf] = __builtin_amdgcn_mfma_f32_16x16x32_bf16(a[mf], b[cf], acc[mf][cf], 0, 0, 0);
    if (wc == 0){
      int ecol = 256 + ((l15 < 12) ? l15 : 11);
      bf16x8 be = *(const bf16x8*)(Wt + (size_t)ecol*128 + kk*32 + l4*8);
      #pragma unroll
      for (int mf = 0; mf < 4; mf++)
        acc_e[mf] = __builtin_amdgcn_mfma_f32_16x16x32_bf16(a[mf], be, acc_e[mf], 0, 0, 0);
    }
  }

  // fc1 epilogue -> alpha into LDS
  #pragma unroll
  for (int mf = 0; mf < 4; mf++){
    int rw[4], ty[4];
    #pragma unroll
    for (int r = 0; r < 4; r++){
      rw[r] = rbase + mf*16 + l4*4 + r;
      ty[r] = (rw[r] < N) ? node_types[rw[r]] : 0;
    }
    #pragma unroll
    for (int p = 0; p < 2; p++){
      int hh = wc*2 + p;
      float w2a = w2[hh*32 + l15];
      float w2b = w2[hh*32 + 16 + l15];
      float b2v = b2[hh];
      #pragma unroll
      for (int r = 0; r < 4; r++){
        const float* sb = sbias + ((size_t)hh*NTYPES + ty[r])*32;
        float z0 = acc[mf][2*p  ][r] + sb[l15];
        float z1 = acc[mf][2*p+1][r] + sb[16 + l15];
        float t0 = 1.f - 2.f/(__expf(2.f*z0) + 1.f);   // tanh
        float t1 = 1.f - 2.f/(__expf(2.f*z1) + 1.f);
        float val = t0*w2a + t1*w2b;
        val += __shfl_xor(val, 1); val += __shfl_xor(val, 2);
        val += __shfl_xor(val, 4); val += __shfl_xor(val, 8);
        if (l15 == 0)
          alds[wr*64 + mf*16 + l4*4 + r][hh] = 1.f/(1.f + __expf(-(val + b2v)));
      }
    }
  }
  __syncthreads();

  // logit epilogue (wc==0 waves own acc_e); D frag: row = l4*4+r, col = l15
  if (wc == 0 && l15 < 12){
    int hq = l15 / 3, et = l15 % 3;
    #pragma unroll
    for (int mf = 0; mf < 4; mf++){
      #pragma unroll
      for (int r = 0; r < 4; r++){
        int rowloc = wr*64 + mf*16 + l4*4 + r;
        int row = blockIdx.x*128 + rowloc;
        if (row < N){
          float s = acc_e[mf][r] * alds[rowloc][hq];
          s = (s >= 0.f) ? s : 0.2f*s;
          lgt[(size_t)row*12 + et*4 + hq] = f2bf(s);
        }
      }
    }
  }
}

// ---------------- gemmV: h @ Wv -> vb[h][n][32] bf16 ----------------

__global__ __launch_bounds__(256) void gemmv_k(
    const float* __restrict__ h, int hstride,
    const short* __restrict__ Wt,
    ushort_t* __restrict__ vb,             // [H][N][32]
    int N)
{
  int lane = threadIdx.x & 63, wvid = threadIdx.x >> 6;
  int wr = wvid >> 1, wc = wvid & 1;
  int l15 = lane & 15, l4 = lane >> 4;
  int rbase = blockIdx.x*128 + wr*64;

  f32x4 acc[4][4] = {};

  #pragma unroll
  for (int kk = 0; kk < 4; kk++){
    bf16x8 a[4], b[4];
    #pragma unroll
    for (int mf = 0; mf < 4; mf++) load_afrag(h, hstride, N, rbase, mf, l15, l4, kk, a[mf]);
    #pragma unroll
    for (int cf = 0; cf < 4; cf++){
      int col = 128 + wc*64 + cf*16 + l15;
      b[cf] = *(const bf16x8*)(Wt + (size_t)col*128 + kk*32 + l4*8);
    }
    #pragma unroll
    for (int mf = 0; mf < 4; mf++)
      #pragma unroll
      for (int cf = 0; cf < 4; cf++)
        acc[mf][cf] = __builtin_amdgcn_mfma_f32_16x16x32_bf16(a[mf], b[cf], acc[mf][cf], 0, 0, 0);
  }

  #pragma unroll
  for (int mf = 0; mf < 4; mf++){
    #pragma unroll
    for (int r = 0; r < 4; r++){
      int row = rbase + mf*16 + l4*4 + r;
      if (row < N){
        #pragma unroll
        for (int cf = 0; cf < 4; cf++){
          int c = wc*64 + cf*16 + l15;        // 0..127
          int hh = c >> 5, d = c & 31;
          vb[((size_t)hh*N + row)*32 + d] = f2bf(acc[mf][cf][r]);
        }
      }
    }
  }
}

// ---------------- k2b fused: logit gather + segment softmax + edge_feat + packed attn ----------------

__global__ __launch_bounds__(256) void k2b_f(
    const ushort_t* __restrict__ lgt, const ushort_t* __restrict__ vb,
    const int* __restrict__ nidx_srtE, const int* __restrict__ edge_off, const int* __restrict__ cnt_e,
    const int* __restrict__ edge_type,
    const int* __restrict__ map_e2n,
    ushort_t* __restrict__ efb,            // [H][E][32] bf16
    ushort_t* __restrict__ attn_pk,        // [NNZ][4] bf16 (node-sorted positions)
    int N, int E)
{
  __shared__ float lbuf[HEADS][CAP];
  __shared__ float mi[HEADS][2];

  int e = blockIdx.x;
  int off = edge_off[e], cnt = cnt_e[e];
  if (cnt == 0) return;
  int lane = threadIdx.x & 63, hh = threadIdx.x >> 6;
  int g = lane & 15, grp = lane >> 4;
  int et = edge_type[e];

  if (cnt <= CAP){
    // phase A: one scalar logit load per entry
    float mloc = -INFINITY;
    for (int j = lane; j < cnt; j += 64){
      float s = lgt_get(lgt, nidx_srtE[off + j], et, hh);
      lbuf[hh][j] = s;
      mloc = fmaxf(mloc, s);
    }
    #pragma unroll
    for (int sh = 32; sh > 0; sh >>= 1) mloc = fmaxf(mloc, __shfl_xor(mloc, sh));
    float m = mloc;

    // phase B: exp-sum + V accumulate (quarter-wave per entry, lane g = dims 2g,2g+1)
    float ef0 = 0.f, ef1 = 0.f, ssum = 0.f;
    for (int jj = 0; jj < cnt; jj += 4){
      int j = jj + grp;
      if (j < cnt){
        float ex = __expf(lbuf[hh][j] - m);
        unsigned vw = *(const unsigned*)&vb[((size_t)hh*N + nidx_srtE[off + j])*32 + 2*g];
        ef0 += ex * bf2f((unsigned short)(vw & 0xffff));
        ef1 += ex * bf2f((unsigned short)(vw >> 16));
        ssum += ex;
      }
    }
    ef0 += __shfl_xor(ef0, 16); ef0 += __shfl_xor(ef0, 32);
    ef1 += __shfl_xor(ef1, 16); ef1 += __shfl_xor(ef1, 32);
    ssum += __shfl_xor(ssum, 16); ssum += __shfl_xor(ssum, 32);
    float inv = 1.0f / ssum;
    if (grp == 0){
      unsigned w = (unsigned)f2bf(ef0*inv) | ((unsigned)f2bf(ef1*inv) << 16);
      *(unsigned*)&efb[((size_t)hh*E + e)*32 + 2*g] = w;
    }
    if (lane == 0){ mi[hh][0] = m; mi[hh][1] = inv; }
    __syncthreads();

    // phase C: wave 0 packs 4 heads' attn, one 8B scattered store per entry
    if (hh == 0){
      for (int j = lane; j < cnt; j += 64){
        int pn = map_e2n[off + j];
        float a0 = __expf(lbuf[0][j] - mi[0][0]) * mi[0][1];
        float a1 = __expf(lbuf[1][j] - mi[1][0]) * mi[1][1];
        float a2 = __expf(lbuf[2][j] - mi[2][0]) * mi[2][1];
        float a3 = __expf(lbuf[3][j] - mi[3][0]) * mi[3][1];
        uint2 o;
        o.x = (unsigned)f2bf(a0) | ((unsigned)f2bf(a1) << 16);
        o.y = (unsigned)f2bf(a2) | ((unsigned)f2bf(a3) << 16);
        *(uint2*)&attn_pk[(size_t)pn*4] = o;
      }
    }
  } else {
    // slow path (cnt > CAP): logits are loads, so just re-load per pass
    float mloc = -INFINITY;
    for (int j = lane; j < cnt; j += 64)
      mloc = fmaxf(mloc, lgt_get(lgt, nidx_srtE[off + j], et, hh));
    #pragma unroll
    for (int sh = 32; sh > 0; sh >>= 1) mloc = fmaxf(mloc, __shfl_xor(mloc, sh));
    float m = mloc;

    float ef0 = 0.f, ef1 = 0.f, ssum = 0.f;
    for (int jj = 0; jj < cnt; jj += 4){
      int j = jj + grp;
      if (j < cnt){
        int n = nidx_srtE[off + j];
        float ex = __expf(lgt_get(lgt, n, et, hh) - m);
        unsigned vw = *(const unsigned*)&vb[((size_t)hh*N + n)*32 + 2*g];
        ef0 += ex * bf2f((unsigned short)(vw & 0xffff));
        ef1 += ex * bf2f((unsigned short)(vw >> 16));
        ssum += ex;
      }
    }
    ef0 += __shfl_xor(ef0, 16); ef0 += __shfl_xor(ef0, 32);
    ef1 += __shfl_xor(ef1, 16); ef1 += __shfl_xor(ef1, 32);
    ssum += __shfl_xor(ssum, 16); ssum += __shfl_xor(ssum, 32);
    float inv = 1.0f / ssum;
    if (grp == 0){
      unsigned w = (unsigned)f2bf(ef0*inv) | ((unsigned)f2bf(ef1*inv) << 16);
      *(unsigned*)&efb[((size_t)hh*E + e)*32 + 2*g] = w;
    }
    for (int j = lane; j < cnt; j += 64){
      int n = nidx_srtE[off + j];
      int pn = map_e2n[off + j];
      float ex = __expf(lgt_get(lgt, n, et, hh) - m);
      attn_pk[(size_t)pn*4 + hh] = f2bf(ex * inv);
    }
  }
}

// ---------------- K2c: per-node block: aggregate + concat heads + residual + LayerNorm ----------------

__global__ __launch_bounds__(128) void k2c(
    const ushort_t* __restrict__ attn_pk, const int* __restrict__ eidx_srtN,
    const int* __restrict__ node_off, const int* __restrict__ cnt_n,
    const ushort_t* __restrict__ efb,
    const float* __restrict__ h_in, int hstride,
    const float* __restrict__ ln_g, const float* __restrict__ ln_b,
    float* __restrict__ out, int out_stride, int out_col, int N, int E)
{
  int n = blockIdx.x;
  int t = threadIdx.x;          // 0..127 : head = t>>5, dim = t&31
  int hh = t >> 5, d = t & 31;
  int off = node_off[n], cnt = cnt_n[n];
  float nf = 0.f;
  for (int j = 0; j < cnt; j++){
    int e = eidx_srtN[off + j];
    uint2 ap = *(const uint2*)&attn_pk[(size_t)(off + j)*4];
    unsigned u = (hh & 2) ? ap.y : ap.x;
    unsigned short us = (hh & 1) ? (unsigned short)(u >> 16) : (unsigned short)(u & 0xffff);
    float av = bf2f(us);
    float ev = bf2f(efb[((size_t)hh*E + e)*32 + d]);
    nf += av * ev;
  }
  float hn = nf + h_in[(size_t)n*hstride + t];   // residual (IN==HID)

  __shared__ float sred[2];
  float s = hn;
  #pragma unroll
  for (int sh = 32; sh > 0; sh >>= 1) s += __shfl_xor(s, sh);
  if ((t & 63) == 0) sred[t >> 6] = s;
  __syncthreads();
  float mu = (sred[0] + sred[1]) * (1.0f/128.0f);
  __syncthreads();
  float dv = hn - mu;
  float s2 = dv*dv;
  #pragma unroll
  for (int sh = 32; sh > 0; sh >>= 1) s2 += __shfl_xor(s2, sh);
  if ((t & 63) == 0) sred[t >> 6] = s2;
  __syncthreads();
  float var = (sred[0] + sred[1]) * (1.0f/128.0f);
  float r = rsqrtf(var + 1e-5f);
  out[(size_t)n*out_stride + out_col + t] = dv * r * ln_g[t] + ln_b[t];
}

// ---------------- x copy into output columns 0..127 ----------------

__global__ __launch_bounds__(256) void xcopy_k(const float* __restrict__ x, float* __restrict__ out, int N)
{
  int i = blockIdx.x*256 + threadIdx.x;   // over N*32 float4s
  if (i >= N*32) return;
  int n = i >> 5, k = i & 31;
  reinterpret_cast<float4*>(out)[(size_t)n*96 + k] = reinterpret_cast<const float4*>(x)[i];
}

// ---------------- launcher ----------------

extern "C" void kernel_launch(void* const* d_in, const int* in_sizes, int n_in,
                              void* d_out, int out_size, void* d_ws, size_t ws_size,
                              hipStream_t stream)
{
  const float* x          = (const float*)d_in[0];
  const int*   node_types = (const int*)  d_in[1];
  const int*   node_idx   = (const int*)  d_in[2];
  const int*   edge_idx   = (const int*)  d_in[3];
  const int*   edge_type  = (const int*)  d_in[4];
  const float* type_query = (const float*)d_in[5];
  const float* fc1_w      = (const float*)d_in[6];
  const float* fc1_b      = (const float*)d_in[7];
  const float* fc2_w      = (const float*)d_in[8];
  const float* fc2_b      = (const float*)d_in[9];
  const float* Wq         = (const float*)d_in[10];
  const float* Wv         = (const float*)d_in[11];
  const float* edge_ctx   = (const float*)d_in[12];
  const float* ln_g       = (const float*)d_in[13];
  const float* ln_b       = (const float*)d_in[14];

  const int N   = in_sizes[1];
  const int NNZ = in_sizes[2];
  const int E   = in_sizes[4];
  const int L   = 2;

  char* ws = (char*)d_ws;
  size_t o = 0;
  auto alloc = [&](size_t bytes)->void*{
    void* p = ws + o;
    o = (o + bytes + 255) & ~(size_t)255;
    return p;
  };
  int* cnt_e     = (int*)alloc((size_t)E*4);
  int* cur_e     = (int*)alloc((size_t)E*4);
  int* edge_off  = (int*)alloc((size_t)(E+1)*4);
  int* cnt_n     = (int*)alloc((size_t)N*4);
  int* cur_n     = (int*)alloc((size_t)N*4);
  int* node_off  = (int*)alloc((size_t)(N+1)*4);
  int* nidx_srtE = (int*)alloc((size_t)NNZ*4);
  int* map_e2n   = (int*)alloc((size_t)NNZ*4);
  int* eidx_srtN = (int*)alloc((size_t)NNZ*4);
  int* bsum      = (int*)alloc((size_t)1024*4);
  ushort_t* attn_pk = (ushort_t*)alloc((size_t)NNZ*4*2);          // [NNZ][4] bf16
  ushort_t* vb      = (ushort_t*)alloc((size_t)HEADS*N*32*2);     // [H][N][32] bf16
  ushort_t* lgt     = (ushort_t*)alloc((size_t)N*12*2);           // [N][ET][H] bf16
  ushort_t* efb     = (ushort_t*)alloc((size_t)HEADS*E*32*2);     // [H][E][32] bf16
  short*    Wt      = (short*)alloc((size_t)L*WTC*128*2);
  float*    sbias   = (float*)alloc((size_t)L*HEADS*NTYPES*32*4);
  if (o > ws_size) return;  // insufficient workspace: bail loudly (output stays wrong)

  hipMemsetAsync(cnt_e, 0, (size_t)E*4, stream);
  hipMemsetAsync(cur_e, 0, (size_t)E*4, stream);
  hipMemsetAsync(cnt_n, 0, (size_t)N*4, stream);
  hipMemsetAsync(cur_n, 0, (size_t)N*4, stream);

  hist_k<<<cdiv(NNZ,256),256,0,stream>>>(node_idx, edge_idx, cnt_e, cnt_n, NNZ);

  int nbE = cdiv(E,1024), nbN = cdiv(N,1024);
  scan_pass1<<<nbE,1024,0,stream>>>(cnt_e, bsum, E);
  scan_pass2<<<1,1024,0,stream>>>(bsum, nbE);
  scan_pass3<<<nbE,1024,0,stream>>>(cnt_e, bsum, edge_off, E);
  scan_pass1<<<nbN,1024,0,stream>>>(cnt_n, bsum, N);
  scan_pass2<<<1,1024,0,stream>>>(bsum, nbN);
  scan_pass3<<<nbN,1024,0,stream>>>(cnt_n, bsum, node_off, N);

  scatter_k<<<cdiv(NNZ,256),256,0,stream>>>(node_idx, edge_idx, edge_off, node_off,
                                            cur_e, cur_n, nidx_srtE, map_e2n, eidx_srtN, NNZ);

  wtprep_k<<<L*256,128,0,stream>>>(fc1_w, Wv, Wt, L);
  wqc_k<<<L*12,128,0,stream>>>(Wq, edge_ctx, Wt);
  sbias_k<<<L*HEADS*NTYPES,32,0,stream>>>(type_query, fc1_w, fc1_b, sbias);

  xcopy_k<<<cdiv(N*32,256),256,0,stream>>>(x, (float*)d_out, N);

  for (int l = 0; l < L; l++){
    const float* hin = (l == 0) ? x : ((const float*)d_out + 128);
    int hstride = (l == 0) ? DIN : (3*DIN);   // 128 or 384

    gemma_k<<<cdiv(N,128),256,0,stream>>>(
        hin, hstride,
        Wt + (size_t)l*WTC*128,
        node_types,
        sbias + (size_t)l*HEADS*NTYPES*32,
        fc2_w + (size_t)l*HEADS*32,
        fc2_b + (size_t)l*HEADS,
        lgt, N);

    gemmv_k<<<cdiv(N,128),256,0,stream>>>(
        hin, hstride,
        Wt + (size_t)l*WTC*128,
        vb, N);

    k2b_f<<<E,256,0,stream>>>(lgt, vb, nidx_srtE, edge_off, cnt_e,
                              edge_type, map_e2n, efb, attn_pk, N, E);

    k2c<<<N,128,0,stream>>>(attn_pk, eidx_srtN, node_off, cnt_n, efb,
                            hin, hstride,
                            ln_g + (size_t)l*DIN, ln_b + (size_t)l*DIN,
                            (float*)d_out, 3*DIN, DIN + l*DIN, N, E);
  }
}